// Round 1
// 530.690 us; speedup vs baseline: 1.2224x; 1.2224x over previous
//
#include <hip/hip_runtime.h>
#include <hip/hip_bf16.h>

#define B_  2
#define S_  2048
#define D_  2048
#define H_  16
#define DH_ 128
#define M_  (B_*S_)   // 4096

typedef __hip_bfloat16 bf16;
typedef float v4f __attribute__((ext_vector_type(4)));
typedef short v8s __attribute__((ext_vector_type(8)));

__device__ __forceinline__ short f2s(float x) {
  bf16 h = __float2bfloat16(x);
  return *reinterpret_cast<const short*>(&h);
}
// load 8 contiguous f32 elems, convert to bf16 bits
__device__ __forceinline__ v8s ld8(const float* p) {
  v4f a = *reinterpret_cast<const v4f*>(p);
  v4f b = *reinterpret_cast<const v4f*>(p + 4);
  v8s r = { f2s(a[0]), f2s(a[1]), f2s(a[2]), f2s(a[3]),
            f2s(b[0]), f2s(b[1]), f2s(b[2]), f2s(b[3]) };
  return r;
}
__device__ __forceinline__ v8s ld8(const bf16* p) {
  return *reinterpret_cast<const v8s*>(p);
}
__device__ __forceinline__ void store_out(bf16* p, float v)  { *p = __float2bfloat16(v); }
__device__ __forceinline__ void store_out(float* p, float v) { *p = v; }

// async 16B global->LDS (direct, no VGPR round-trip). LDS dest is
// wave-uniform base + lane*16; global src is per-lane.
__device__ __forceinline__ void gll16(const bf16* g, bf16* l) {
  __builtin_amdgcn_global_load_lds((const __attribute__((address_space(1))) void*)g,
                                   (__attribute__((address_space(3))) void*)l,
                                   16, 0, 0);
}

// streaming f32 -> bf16 convert, 8 elems/thread
__global__ __launch_bounds__(256) void cvt_f32_bf16(const float* __restrict__ in,
                                                    bf16* __restrict__ out, int n8) {
  int i = blockIdx.x * 256 + threadIdx.x;
  if (i >= n8) return;
  *reinterpret_cast<v8s*>(out + (size_t)i * 8) = ld8(in + (size_t)i * 8);
}

// C = A @ W^T + bias ; A [M,K] bf16 row-major, W [N,K] bf16 row-major.
// MODE 0: Q -> [B,H,S,dh] scaled by 1/sqrt(dh)*log2(e)
// MODE 1: K -> [B,H,S,dh]
// MODE 2: V -> [B,H,dh,S]  (transposed for PV fragment loads)
// MODE 3: plain [M,N]   (f32 out for the final projection)
// m97 structure: 128x128 tile, BK=32, global_load_lds width-16 staging.
template <int MODE, typename TOUT>
__global__ __launch_bounds__(256) void gemm_bt(const bf16* __restrict__ A,
                                               const bf16* __restrict__ W,
                                               const float* __restrict__ bias,
                                               TOUT* __restrict__ out) {
  __shared__ __align__(16) bf16 As[128 * 32];
  __shared__ __align__(16) bf16 Bs[128 * 32];
  const int tid  = threadIdx.x;
  const int lane = tid & 63, wave = tid >> 6;
  const int wm = wave >> 1, wn = wave & 1;
  const int quad = lane >> 4, l16 = lane & 15;
  const int bm = blockIdx.y * 128, bn = blockIdx.x * 128;

  // staging: thread t covers row (t>>2), col (t&3)*8 of the 128x32 tile.
  // LDS linear layout [row][32] matches lane*16B exactly (rows 0-63 round 0,
  // rows 64-127 round 1).
  const bf16* aptr = A + (size_t)(bm + (tid >> 2)) * D_ + (tid & 3) * 8;
  const bf16* bptr = W + (size_t)(bn + (tid >> 2)) * D_ + (tid & 3) * 8;
  bf16* lA0 = As + wave * 512;
  bf16* lA1 = As + 2048 + wave * 512;
  bf16* lB0 = Bs + wave * 512;
  bf16* lB1 = Bs + 2048 + wave * 512;

  v4f acc[4][4] = {};
  for (int k0 = 0; k0 < D_; k0 += 32) {
    gll16(aptr + k0,                    lA0);
    gll16(aptr + (size_t)64 * D_ + k0,  lA1);
    gll16(bptr + k0,                    lB0);
    gll16(bptr + (size_t)64 * D_ + k0,  lB1);
    __syncthreads();
    v8s af[4], bfr[4];
#pragma unroll
    for (int mi = 0; mi < 4; ++mi)
      af[mi] = *reinterpret_cast<const v8s*>(&As[(wm * 64 + mi * 16 + l16) * 32 + quad * 8]);
#pragma unroll
    for (int ni = 0; ni < 4; ++ni)
      bfr[ni] = *reinterpret_cast<const v8s*>(&Bs[(wn * 64 + ni * 16 + l16) * 32 + quad * 8]);
#pragma unroll
    for (int mi = 0; mi < 4; ++mi)
#pragma unroll
      for (int ni = 0; ni < 4; ++ni)
        acc[mi][ni] = __builtin_amdgcn_mfma_f32_16x16x32_bf16(af[mi], bfr[ni], acc[mi][ni], 0, 0, 0);
    __syncthreads();
  }

  constexpr float QSCALE = 0.12752003912f;  // 1/sqrt(128) * log2(e)
#pragma unroll
  for (int ni = 0; ni < 4; ++ni) {
    const int n = bn + wn * 64 + ni * 16 + l16;
    const float bv = bias[n];
#pragma unroll
    for (int mi = 0; mi < 4; ++mi) {
      const int m0 = bm + wm * 64 + mi * 16 + quad * 4;
#pragma unroll
      for (int r = 0; r < 4; ++r) {
        const int m = m0 + r;           // row m: (b,s). col n: (h,d)
        float v = acc[mi][ni][r] + bv;
        size_t idx;
        if (MODE == 0 || MODE == 1) {
          if (MODE == 0) v *= QSCALE;
          int b = m >> 11, s = m & (S_ - 1);
          int h = n >> 7,  d = n & (DH_ - 1);
          idx = ((size_t)(b * H_ + h) * S_ + s) * DH_ + d;
        } else if (MODE == 2) {
          int b = m >> 11, s = m & (S_ - 1);
          int h = n >> 7,  d = n & (DH_ - 1);
          idx = ((size_t)(b * H_ + h) * DH_ + d) * S_ + s;
        } else {
          idx = (size_t)m * D_ + n;
        }
        store_out(out + idx, v);
      }
    }
  }
}

// Flash attention, causal. Q/K: [B,H,S,dh], Vt: [B,H,dh,S] (all bf16). Out: [B,S,D] bf16.
// Block = 64 Q rows (4 waves x 16 rows), K-tile = 64 keys.
#define KSTR 136   // Ks row stride (elems): 272 B -> 16B-aligned rows
#define VSTR 72    // Vs row stride (elems): 144 B
__global__ __launch_bounds__(256) void attn_fused(const bf16* __restrict__ Q,
                                                  const bf16* __restrict__ K,
                                                  const bf16* __restrict__ Vt,
                                                  bf16* __restrict__ Oa) {
  __shared__ __align__(16) bf16 Ks[64 * KSTR];   // [key][d], padded
  __shared__ __align__(16) bf16 Vs[128 * VSTR];  // [d][key], padded
  __shared__ __align__(16) bf16 Ps[4][16 * 72];  // per-wave P, padded stride 72
  const int tid  = threadIdx.x;
  const int lane = tid & 63, wave = tid >> 6;
  const int quad = lane >> 4, l16 = lane & 15;
  // longest-first scheduling: work per block ~ (qt+1); reverse the mapping so
  // the big blocks launch first and the causal tail doesn't straggle.
  const int qt = (int)gridDim.x - 1 - (int)blockIdx.x;
  const int bh = blockIdx.y;
  const int b = bh >> 4, h = bh & 15;
  const bf16* Qh = Q  + (size_t)bh * S_ * DH_;
  const bf16* Kh = K  + (size_t)bh * S_ * DH_;
  const bf16* Vh = Vt + (size_t)bh * DH_ * S_;

  const int qrow0 = qt * 64 + wave * 16;
  v8s qf[4];
#pragma unroll
  for (int kk = 0; kk < 4; ++kk)
    qf[kk] = *reinterpret_cast<const v8s*>(&Qh[(size_t)(qrow0 + l16) * DH_ + kk * 32 + quad * 8]);

  v4f acc_o[8] = {};
  float m_i[4], l_i[4];
#pragma unroll
  for (int r = 0; r < 4; ++r) { m_i[r] = -1.0e30f; l_i[r] = 0.f; }

  for (int kt = 0; kt <= qt; ++kt) {
    const int kbase = kt * 64;
#pragma unroll
    for (int c = 0; c < 4; ++c) {
      int kr = c * 16 + (tid >> 4);     // 16 K-rows per round
      *reinterpret_cast<v8s*>(&Ks[kr * KSTR + (tid & 15) * 8]) =
          *reinterpret_cast<const v8s*>(&Kh[(size_t)(kbase + kr) * DH_ + (tid & 15) * 8]);
      int vr2 = c * 32 + (tid >> 3);    // 32 V-rows per round
      *reinterpret_cast<v8s*>(&Vs[vr2 * VSTR + (tid & 7) * 8]) =
          *reinterpret_cast<const v8s*>(&Vh[(size_t)vr2 * S_ + kbase + (tid & 7) * 8]);
    }
    __syncthreads();

    // S = Q K^T (Q pre-scaled by 1/sqrt(dh)*log2e)
    v4f sc[4];
#pragma unroll
    for (int nt = 0; nt < 4; ++nt) {
      v4f a = {};
#pragma unroll
      for (int kk = 0; kk < 4; ++kk) {
        v8s kf = *reinterpret_cast<const v8s*>(&Ks[(nt * 16 + l16) * KSTR + (kk * 4 + quad) * 8]);
        a = __builtin_amdgcn_mfma_f32_16x16x32_bf16(qf[kk], kf, a, 0, 0, 0);
      }
      sc[nt] = a;
    }
    if (kt == qt) {   // causal mask only on the diagonal tile
#pragma unroll
      for (int nt = 0; nt < 4; ++nt)
#pragma unroll
        for (int r = 0; r < 4; ++r) {
          int kc = kbase + nt * 16 + l16;
          int qr = qrow0 + quad * 4 + r;
          if (kc > qr) sc[nt][r] = -1.0e30f;
        }
    }
    // online softmax; C-layout: row = quad*4 + r, col = nt*16 + l16
#pragma unroll
    for (int r = 0; r < 4; ++r) {
      float mx = fmaxf(fmaxf(sc[0][r], sc[1][r]), fmaxf(sc[2][r], sc[3][r]));
      mx = fmaxf(mx, __shfl_xor(mx, 1));
      mx = fmaxf(mx, __shfl_xor(mx, 2));
      mx = fmaxf(mx, __shfl_xor(mx, 4));
      mx = fmaxf(mx, __shfl_xor(mx, 8));
      float mnew = fmaxf(mx, m_i[r]);
      float alpha = exp2f(m_i[r] - mnew);
      m_i[r] = mnew;
      l_i[r] *= alpha;
#pragma unroll
      for (int nt8 = 0; nt8 < 8; ++nt8) acc_o[nt8][r] *= alpha;
      float s0 = exp2f(sc[0][r] - mnew);
      float s1 = exp2f(sc[1][r] - mnew);
      float s2 = exp2f(sc[2][r] - mnew);
      float s3 = exp2f(sc[3][r] - mnew);
      sc[0][r] = s0; sc[1][r] = s1; sc[2][r] = s2; sc[3][r] = s3;
      float t = s0 + s1 + s2 + s3;
      t += __shfl_xor(t, 1); t += __shfl_xor(t, 2);
      t += __shfl_xor(t, 4); t += __shfl_xor(t, 8);
      l_i[r] += t;
    }
    // P: C-layout regs -> LDS (bf16) -> A-layout frags
#pragma unroll
    for (int nt = 0; nt < 4; ++nt)
#pragma unroll
      for (int r = 0; r < 4; ++r)
        Ps[wave][(quad * 4 + r) * 72 + nt * 16 + l16] = __float2bfloat16(sc[nt][r]);
    __syncthreads();
    // O += P V
#pragma unroll
    for (int kk2 = 0; kk2 < 2; ++kk2) {
      v8s pf = *reinterpret_cast<const v8s*>(&Ps[wave][l16 * 72 + kk2 * 32 + quad * 8]);
#pragma unroll
      for (int nt8 = 0; nt8 < 8; ++nt8) {
        v8s vf = *reinterpret_cast<const v8s*>(&Vs[(nt8 * 16 + l16) * VSTR + (kk2 * 4 + quad) * 8]);
        acc_o[nt8] = __builtin_amdgcn_mfma_f32_16x16x32_bf16(pf, vf, acc_o[nt8], 0, 0, 0);
      }
    }
    __syncthreads();
  }

#pragma unroll
  for (int r = 0; r < 4; ++r) {
    const float inv = 1.0f / l_i[r];
    const int srow = qrow0 + quad * 4 + r;
#pragma unroll
    for (int nt8 = 0; nt8 < 8; ++nt8)
      Oa[((size_t)b * S_ + srow) * D_ + h * DH_ + nt8 * 16 + l16] =
          __float2bfloat16(acc_o[nt8][r] * inv);
  }
}

extern "C" void kernel_launch(void* const* d_in, const int* in_sizes, int n_in,
                              void* d_out, int out_size, void* d_ws, size_t ws_size,
                              hipStream_t stream) {
  // Canary: all-zero output (absmax exactly 3.5625) signals a tripped assumption.
  if (n_in != 9 ||
      in_sizes[0] != M_ * D_ ||
      in_sizes[1] != D_ * D_ || in_sizes[2] != D_ ||
      in_sizes[3] != D_ * D_ || in_sizes[4] != D_ ||
      in_sizes[5] != D_ * D_ || in_sizes[6] != D_ ||
      in_sizes[7] != D_ * D_ || in_sizes[8] != D_ ||
      out_size != M_ * D_)
    return;

  const float* x  = (const float*)d_in[0];
  const float* Wq = (const float*)d_in[1];
  const float* bq = (const float*)d_in[2];
  const float* Wk = (const float*)d_in[3];
  const float* bk = (const float*)d_in[4];
  const float* Wv = (const float*)d_in[5];
  const float* bv = (const float*)d_in[6];
  const float* Wo = (const float*)d_in[7];
  const float* bo = (const float*)d_in[8];
  float* out = (float*)d_out;   // OUTPUT IS FLOAT32 (reference output dtype)

  const size_t NT = (size_t)M_ * D_;   // 8388608 elems per tensor
  // Buffer plan (zero extra ws vs previous version):
  //   d_out (33.6 MB f32):  [0,16.8) qws (bf16 Q, dead before final GEMM)
  //                         [16.8,33.6) x_bf16 (dead before final GEMM)
  //   ws (50.3 MB, proven): kws | vtw | aws
  //     - Wq/Wk/Wv bf16 time-share the aws region (dead before attn writes it)
  //     - Wo bf16 parks in kws region (kws dead after attn)
  bf16* qws   = (bf16*)d_out;
  bf16* xbf   = (bf16*)d_out + NT;
  bf16* kws   = (bf16*)d_ws;
  bf16* vtw   = kws + NT;
  bf16* aws   = vtw + NT;
  bf16* wslot = aws;   // 8.4 MB W slot inside 16.8 MB aws region
  bf16* wo_s  = kws;   // Wo slot inside kws region (post-attn)

  const int N8X = M_ * D_ / 8;   // 1048576
  const int N8W = D_ * D_ / 8;   // 524288

  dim3 gg(D_ / 128, M_ / 128), bb(256);

  cvt_f32_bf16<<<N8X / 256, bb, 0, stream>>>(x, xbf, N8X);

  cvt_f32_bf16<<<N8W / 256, bb, 0, stream>>>(Wq, wslot, N8W);
  gemm_bt<0, bf16><<<gg, bb, 0, stream>>>(xbf, wslot, bq, qws);

  cvt_f32_bf16<<<N8W / 256, bb, 0, stream>>>(Wk, wslot, N8W);
  gemm_bt<1, bf16><<<gg, bb, 0, stream>>>(xbf, wslot, bk, kws);

  cvt_f32_bf16<<<N8W / 256, bb, 0, stream>>>(Wv, wslot, N8W);
  gemm_bt<2, bf16><<<gg, bb, 0, stream>>>(xbf, wslot, bv, vtw);

  attn_fused<<<dim3(S_ / 64, B_ * H_), bb, 0, stream>>>(qws, kws, vtw, aws);

  cvt_f32_bf16<<<N8W / 256, bb, 0, stream>>>(Wo, wo_s, N8W);
  gemm_bt<3, float><<<gg, bb, 0, stream>>>(aws, wo_s, bo, out);
}

// Round 2
// 475.335 us; speedup vs baseline: 1.3647x; 1.1165x over previous
//
#include <hip/hip_runtime.h>
#include <hip/hip_bf16.h>

#define B_  2
#define S_  2048
#define D_  2048
#define H_  16
#define DH_ 128
#define M_  (B_*S_)   // 4096

typedef __hip_bfloat16 bf16;
typedef float v4f __attribute__((ext_vector_type(4)));
typedef short v8s __attribute__((ext_vector_type(8)));

__device__ __forceinline__ short f2s(float x) {
  bf16 h = __float2bfloat16(x);
  return *reinterpret_cast<const short*>(&h);
}
// load 8 contiguous f32 elems, convert to bf16 bits
__device__ __forceinline__ v8s ld8(const float* p) {
  v4f a = *reinterpret_cast<const v4f*>(p);
  v4f b = *reinterpret_cast<const v4f*>(p + 4);
  v8s r = { f2s(a[0]), f2s(a[1]), f2s(a[2]), f2s(a[3]),
            f2s(b[0]), f2s(b[1]), f2s(b[2]), f2s(b[3]) };
  return r;
}
__device__ __forceinline__ v8s ld8(const bf16* p) {
  return *reinterpret_cast<const v8s*>(p);
}
__device__ __forceinline__ void store_out(bf16* p, float v)  { *p = __float2bfloat16(v); }
__device__ __forceinline__ void store_out(float* p, float v) { *p = v; }

// async 16B global->LDS (direct, no VGPR round-trip). LDS dest is
// wave-uniform base + lane*16; global src is per-lane.
__device__ __forceinline__ void gll16(const bf16* g, bf16* l) {
  __builtin_amdgcn_global_load_lds((const __attribute__((address_space(1))) void*)g,
                                   (__attribute__((address_space(3))) void*)l,
                                   16, 0, 0);
}

// streaming f32 -> bf16 convert, 8 elems/thread
__global__ __launch_bounds__(256) void cvt_f32_bf16(const float* __restrict__ in,
                                                    bf16* __restrict__ out, int n8) {
  int i = blockIdx.x * 256 + threadIdx.x;
  if (i >= n8) return;
  *reinterpret_cast<v8s*>(out + (size_t)i * 8) = ld8(in + (size_t)i * 8);
}

// C = A @ W^T + bias ; A [M,K] bf16 row-major, W [N,K] bf16 row-major.
// MODE 0: Q -> [B,H,S,dh] scaled by 1/sqrt(dh)*log2(e)
// MODE 1: K -> [B,H,S,dh]
// MODE 2: V -> [B,H,dh,S]  (transposed for PV fragment loads)
// MODE 3: plain [M,N]   (f32 out for the final projection)
// m97 structure: 128x128 tile, BK=32, global_load_lds width-16 staging.
template <int MODE, typename TOUT>
__global__ __launch_bounds__(256) void gemm_bt(const bf16* __restrict__ A,
                                               const bf16* __restrict__ W,
                                               const float* __restrict__ bias,
                                               TOUT* __restrict__ out) {
  __shared__ __align__(16) bf16 As[128 * 32];
  __shared__ __align__(16) bf16 Bs[128 * 32];
  const int tid  = threadIdx.x;
  const int lane = tid & 63, wave = tid >> 6;
  const int wm = wave >> 1, wn = wave & 1;
  const int quad = lane >> 4, l16 = lane & 15;
  const int bm = blockIdx.y * 128, bn = blockIdx.x * 128;

  const bf16* aptr = A + (size_t)(bm + (tid >> 2)) * D_ + (tid & 3) * 8;
  const bf16* bptr = W + (size_t)(bn + (tid >> 2)) * D_ + (tid & 3) * 8;
  bf16* lA0 = As + wave * 512;
  bf16* lA1 = As + 2048 + wave * 512;
  bf16* lB0 = Bs + wave * 512;
  bf16* lB1 = Bs + 2048 + wave * 512;

  v4f acc[4][4] = {};
  for (int k0 = 0; k0 < D_; k0 += 32) {
    gll16(aptr + k0,                    lA0);
    gll16(aptr + (size_t)64 * D_ + k0,  lA1);
    gll16(bptr + k0,                    lB0);
    gll16(bptr + (size_t)64 * D_ + k0,  lB1);
    __syncthreads();
    v8s af[4], bfr[4];
#pragma unroll
    for (int mi = 0; mi < 4; ++mi)
      af[mi] = *reinterpret_cast<const v8s*>(&As[(wm * 64 + mi * 16 + l16) * 32 + quad * 8]);
#pragma unroll
    for (int ni = 0; ni < 4; ++ni)
      bfr[ni] = *reinterpret_cast<const v8s*>(&Bs[(wn * 64 + ni * 16 + l16) * 32 + quad * 8]);
#pragma unroll
    for (int mi = 0; mi < 4; ++mi)
#pragma unroll
      for (int ni = 0; ni < 4; ++ni)
        acc[mi][ni] = __builtin_amdgcn_mfma_f32_16x16x32_bf16(af[mi], bfr[ni], acc[mi][ni], 0, 0, 0);
    __syncthreads();
  }

  constexpr float QSCALE = 0.12752003912f;  // 1/sqrt(128) * log2(e)
#pragma unroll
  for (int ni = 0; ni < 4; ++ni) {
    const int n = bn + wn * 64 + ni * 16 + l16;
    const float bv = bias[n];
#pragma unroll
    for (int mi = 0; mi < 4; ++mi) {
      const int m0 = bm + wm * 64 + mi * 16 + quad * 4;
#pragma unroll
      for (int r = 0; r < 4; ++r) {
        const int m = m0 + r;           // row m: (b,s). col n: (h,d)
        float v = acc[mi][ni][r] + bv;
        size_t idx;
        if (MODE == 0 || MODE == 1) {
          if (MODE == 0) v *= QSCALE;
          int b = m >> 11, s = m & (S_ - 1);
          int h = n >> 7,  d = n & (DH_ - 1);
          idx = ((size_t)(b * H_ + h) * S_ + s) * DH_ + d;
        } else if (MODE == 2) {
          int b = m >> 11, s = m & (S_ - 1);
          int h = n >> 7,  d = n & (DH_ - 1);
          idx = ((size_t)(b * H_ + h) * DH_ + d) * S_ + s;
        } else {
          idx = (size_t)m * D_ + n;
        }
        store_out(out + idx, v);
      }
    }
  }
}

// Flash attention, causal. Q/K: [B,H,S,dh], Vt: [B,H,dh,S] (all bf16). Out: [B,S,D] bf16.
// Block = 128 Q rows (8 waves x 16 rows), K-tile = 64 keys, 512 threads.
// K/V staged via global_load_lds (linear LDS dest) with XOR-swizzled GLOBAL
// source; reads apply the same XOR (rule 21: both-sides-or-neither).
#define QBLK 128
__global__ __launch_bounds__(512, 4) void attn_fused(const bf16* __restrict__ Q,
                                                     const bf16* __restrict__ K,
                                                     const bf16* __restrict__ Vt,
                                                     bf16* __restrict__ Oa) {
  __shared__ __align__(16) bf16 Ks[64 * 128];   // [key][d] linear; 16B-block c holds global c^(key&7)
  __shared__ __align__(16) bf16 Vs[128 * 64];   // [d][key] linear; 16B-block c holds global c^(d&7)
  __shared__ __align__(16) bf16 Ps[8][16 * 72]; // per-wave P, padded stride 72
  const int tid  = threadIdx.x;
  const int lane = tid & 63, wave = tid >> 6;
  const int quad = lane >> 4, l16 = lane & 15;
  const int swz  = l16 & 7;
  // longest-first: work per block ~ qt, launch big blocks first.
  const int qt = (int)gridDim.x - 1 - (int)blockIdx.x;
  const int bh = blockIdx.y;
  const int b = bh >> 4, h = bh & 15;
  const bf16* Qh = Q  + (size_t)bh * S_ * DH_;
  const bf16* Kh = K  + (size_t)bh * S_ * DH_;
  const bf16* Vh = Vt + (size_t)bh * DH_ * S_;

  const int qrow0 = qt * QBLK + wave * 16;
  v8s qf[4];
#pragma unroll
  for (int kk = 0; kk < 4; ++kk)
    qf[kk] = *reinterpret_cast<const v8s*>(&Qh[(size_t)(qrow0 + l16) * DH_ + kk * 32 + quad * 8]);

  v4f acc_o[8] = {};
  float m_i[4], l_i[4];
#pragma unroll
  for (int r = 0; r < 4; ++r) { m_i[r] = -1.0e30f; l_i[r] = 0.f; }

  const int nkt = 2 * qt + 2;
  for (int kt = 0; kt < nkt; ++kt) {
    const int kbase = kt * 64;
    // --- stage K (64x256B) and V (128x128B) via global_load_lds, 2 rounds ---
#pragma unroll
    for (int rr = 0; rr < 2; ++rr) {
      const int g = rr * 512 + tid;
      const int krow = g >> 4, kc = g & 15;           // K: 16 x 16B blocks/row
      gll16(Kh + (size_t)(kbase + krow) * DH_ + ((kc ^ (krow & 7)) << 3),
            Ks + rr * 4096 + wave * 512);
      const int vrow = g >> 3, vc = g & 7;            // V: 8 x 16B blocks/row
      gll16(Vh + (size_t)vrow * S_ + kbase + ((vc ^ (vrow & 7)) << 3),
            Vs + rr * 4096 + wave * 512);
    }
    __syncthreads();   // drains vmcnt (gll16) + all waves staged

    const bool active = (kbase <= qrow0 + 15);
    if (active) {
      // S = Q K^T (Q pre-scaled by 1/sqrt(dh)*log2e)
      v4f sc[4];
      __builtin_amdgcn_s_setprio(1);
#pragma unroll
      for (int nt = 0; nt < 4; ++nt) {
        v4f a = {};
#pragma unroll
        for (int kk = 0; kk < 4; ++kk) {
          v8s kf = *reinterpret_cast<const v8s*>(
              &Ks[(nt * 16 + l16) * 128 + (((kk * 4 + quad) ^ swz) << 3)]);
          a = __builtin_amdgcn_mfma_f32_16x16x32_bf16(qf[kk], kf, a, 0, 0, 0);
        }
        sc[nt] = a;
      }
      __builtin_amdgcn_s_setprio(0);
      if (kbase + 63 > qrow0) {   // diagonal tile: causal mask
#pragma unroll
        for (int nt = 0; nt < 4; ++nt)
#pragma unroll
          for (int r = 0; r < 4; ++r) {
            int kc2 = kbase + nt * 16 + l16;
            int qr = qrow0 + quad * 4 + r;
            if (kc2 > qr) sc[nt][r] = -1.0e30f;
          }
      }
      // online softmax; C-layout: row = quad*4 + r, col = nt*16 + l16
#pragma unroll
      for (int r = 0; r < 4; ++r) {
        float mx = fmaxf(fmaxf(sc[0][r], sc[1][r]), fmaxf(sc[2][r], sc[3][r]));
        mx = fmaxf(mx, __shfl_xor(mx, 1));
        mx = fmaxf(mx, __shfl_xor(mx, 2));
        mx = fmaxf(mx, __shfl_xor(mx, 4));
        mx = fmaxf(mx, __shfl_xor(mx, 8));
        // T13 defer-max: only rescale when max grew by >8 (log2 domain);
        // P then bounded by 2^8, fine in bf16/f32.
        if (mx > m_i[r] + 8.0f) {
          float alpha = exp2f(m_i[r] - mx);
          m_i[r] = mx;
          l_i[r] *= alpha;
#pragma unroll
          for (int nt8 = 0; nt8 < 8; ++nt8) acc_o[nt8][r] *= alpha;
        }
        const float mm = m_i[r];
        float s0 = exp2f(sc[0][r] - mm);
        float s1 = exp2f(sc[1][r] - mm);
        float s2 = exp2f(sc[2][r] - mm);
        float s3 = exp2f(sc[3][r] - mm);
        sc[0][r] = s0; sc[1][r] = s1; sc[2][r] = s2; sc[3][r] = s3;
        float t = s0 + s1 + s2 + s3;
        t += __shfl_xor(t, 1); t += __shfl_xor(t, 2);
        t += __shfl_xor(t, 4); t += __shfl_xor(t, 8);
        l_i[r] += t;
      }
      // P: C-layout regs -> per-wave LDS (bf16) -> A-layout frags
#pragma unroll
      for (int nt = 0; nt < 4; ++nt)
#pragma unroll
        for (int r = 0; r < 4; ++r)
          Ps[wave][(quad * 4 + r) * 72 + nt * 16 + l16] = __float2bfloat16(sc[nt][r]);
      // own-wave write->read ordering only; no cross-wave dep -> no barrier
      asm volatile("s_waitcnt lgkmcnt(0)" ::: "memory");
      // O += P V
      __builtin_amdgcn_s_setprio(1);
#pragma unroll
      for (int kk2 = 0; kk2 < 2; ++kk2) {
        v8s pf = *reinterpret_cast<const v8s*>(&Ps[wave][l16 * 72 + kk2 * 32 + quad * 8]);
#pragma unroll
        for (int nt8 = 0; nt8 < 8; ++nt8) {
          v8s vf = *reinterpret_cast<const v8s*>(
              &Vs[(nt8 * 16 + l16) * 64 + (((kk2 * 4 + quad) ^ swz) << 3)]);
          acc_o[nt8] = __builtin_amdgcn_mfma_f32_16x16x32_bf16(pf, vf, acc_o[nt8], 0, 0, 0);
        }
      }
      __builtin_amdgcn_s_setprio(0);
    }
    __syncthreads();   // Ks/Vs consumed; safe to restage
  }

#pragma unroll
  for (int r = 0; r < 4; ++r) {
    const float inv = 1.0f / l_i[r];
    const int srow = qrow0 + quad * 4 + r;
#pragma unroll
    for (int nt8 = 0; nt8 < 8; ++nt8)
      Oa[((size_t)b * S_ + srow) * D_ + h * DH_ + nt8 * 16 + l16] =
          __float2bfloat16(acc_o[nt8][r] * inv);
  }
}

extern "C" void kernel_launch(void* const* d_in, const int* in_sizes, int n_in,
                              void* d_out, int out_size, void* d_ws, size_t ws_size,
                              hipStream_t stream) {
  // Canary: all-zero output (absmax exactly 3.5625) signals a tripped assumption.
  if (n_in != 9 ||
      in_sizes[0] != M_ * D_ ||
      in_sizes[1] != D_ * D_ || in_sizes[2] != D_ ||
      in_sizes[3] != D_ * D_ || in_sizes[4] != D_ ||
      in_sizes[5] != D_ * D_ || in_sizes[6] != D_ ||
      in_sizes[7] != D_ * D_ || in_sizes[8] != D_ ||
      out_size != M_ * D_)
    return;

  const float* x  = (const float*)d_in[0];
  const float* Wq = (const float*)d_in[1];
  const float* bq = (const float*)d_in[2];
  const float* Wk = (const float*)d_in[3];
  const float* bk = (const float*)d_in[4];
  const float* Wv = (const float*)d_in[5];
  const float* bv = (const float*)d_in[6];
  const float* Wo = (const float*)d_in[7];
  const float* bo = (const float*)d_in[8];
  float* out = (float*)d_out;   // OUTPUT IS FLOAT32 (reference output dtype)

  const size_t NT = (size_t)M_ * D_;   // 8388608 elems per tensor
  // Buffer plan:
  //   d_out (33.6 MB f32):  [0,16.8) qws (bf16 Q), [16.8,33.6) x_bf16
  //     both dead before the final GEMM overwrites d_out.
  //   ws (50.3 MB): kws | vtw | aws
  //     Wq/Wk/Wv bf16 time-share aws (dead before attn writes it);
  //     Wo bf16 parks in kws (dead after attn).
  bf16* qws   = (bf16*)d_out;
  bf16* xbf   = (bf16*)d_out + NT;
  bf16* kws   = (bf16*)d_ws;
  bf16* vtw   = kws + NT;
  bf16* aws   = vtw + NT;
  bf16* wslot = aws;
  bf16* wo_s  = kws;

  const int N8X = M_ * D_ / 8;   // 1048576
  const int N8W = D_ * D_ / 8;   // 524288

  dim3 gg(D_ / 128, M_ / 128), bb(256);

  cvt_f32_bf16<<<N8X / 256, bb, 0, stream>>>(x, xbf, N8X);

  cvt_f32_bf16<<<N8W / 256, bb, 0, stream>>>(Wq, wslot, N8W);
  gemm_bt<0, bf16><<<gg, bb, 0, stream>>>(xbf, wslot, bq, qws);

  cvt_f32_bf16<<<N8W / 256, bb, 0, stream>>>(Wk, wslot, N8W);
  gemm_bt<1, bf16><<<gg, bb, 0, stream>>>(xbf, wslot, bk, kws);

  cvt_f32_bf16<<<N8W / 256, bb, 0, stream>>>(Wv, wslot, N8W);
  gemm_bt<2, bf16><<<gg, bb, 0, stream>>>(xbf, wslot, bv, vtw);

  attn_fused<<<dim3(S_ / QBLK, B_ * H_), dim3(512), 0, stream>>>(qws, kws, vtw, aws);

  cvt_f32_bf16<<<N8W / 256, bb, 0, stream>>>(Wo, wo_s, N8W);
  gemm_bt<3, float><<<gg, bb, 0, stream>>>(aws, wo_s, bo, out);
}